// Round 13
// baseline (69.707 us; speedup 1.0000x reference)
//
#include <hip/hip_runtime.h>

// MPS periodic chain: psi_b = tr( prod_{i=0..63} (param[i][x[b,i]] + I) )
// d_out: float32[4096], out[b] = log|psi_b|.
//
// Pipeline:
//  prep:      T = param + I -> bf16 (Tn row-major, Tt transposed)
//  build_p8:  2048 waves; wave (s,c) computes P8[s][c] = prod_j T[8s+j][bit]
//             right-to-left in registers. Stores P8n (s<7), P8t (s==3, s==7).
//  chain:     TWO waves per batch (split halves):
//               half0: M_L = P8[0]( P8[1] (P8[2] P8[3]) )   (2 shuffle-mults + full MFMA)
//                      -> store bf16 row-major to LDS (72-stride pad)
//               half1: M_R = P8[4] P8[5] P8[6] P8[7]        (3 shuffle-mults)
//               sync; half1: psi = tr(M_L * M_R) via diagonal tiles; out[b]=log|psi|
//             Serial matmul depth 7 -> 4 (latency-bound kernel).
//
// MFMA v_mfma_f32_16x16x32_bf16 layouts (verified rounds 9/11/12):
//  A: lane l holds X[m=(l&15)+16mi][k=8*(l>>4)+32ks+j], j=0..7
//  B: lane l holds Y[k=8*(l>>4)+32ks+j][n=(l&15)+16nj]
//  D: lane l reg r holds C[m=4*(l>>4)+r+16mi][n=(l&15)+16nj]
// D->B: dest lane (p',c) word w of B[ks][nj] = pk[mi=2ks+(p'>>1)][nj][h=w&1]
//       from src lane c+32*(p'&1)+16*(w>>1); ALL shuffles convergent, select after.

typedef __attribute__((ext_vector_type(8))) __bf16 bf16x8;
typedef __attribute__((ext_vector_type(4))) float f32x4;
typedef __attribute__((ext_vector_type(4))) int   int4v;

#define MFMA16(a, b, c) __builtin_amdgcn_mfma_f32_16x16x32_bf16((a), (b), (c), 0, 0, 0)

union frag_u { int4v i; bf16x8 v; };

__device__ __forceinline__ unsigned short f2bf(float f) {
  union { float f; unsigned u; } v; v.f = f;
  unsigned r = v.u + 0x7fffu + ((v.u >> 16) & 1u);   // RNE
  return (unsigned short)(r >> 16);
}

// ---------------- phase 0: param + I -> bf16, normal + transposed ----------------
__global__ __launch_bounds__(256) void prep_kernel(const float* __restrict__ p,
                                                   unsigned short* __restrict__ Tn,
                                                   unsigned short* __restrict__ Tt) {
  int t = blockIdx.x * 256 + threadIdx.x;      // 0 .. 524287
  int j  = t & 63;
  int i  = (t >> 6) & 63;
  int pq = t >> 12;                            // [site][digit] 0..127
  float v = p[t] + ((i == j) ? 1.0f : 0.0f);
  unsigned short h = f2bf(v);
  Tn[t] = h;
  Tt[(((size_t)pq) << 12) + (size_t)j * 64 + i] = h;
}

// ---------------- phase 1: P8 table, one wave per (segment, combo) ----------------
__global__ __launch_bounds__(256) void build_p8_kernel(const unsigned short* __restrict__ Tn,
                                                       const unsigned short* __restrict__ Tt,
                                                       unsigned short* __restrict__ P8n,
                                                       unsigned short* __restrict__ P8t) {
  const int tid = threadIdx.x;
  const int l   = tid & 63;
  const int w   = blockIdx.x * 4 + (tid >> 6);   // 0..2047
  const int s   = w >> 8, cmb = w & 255;         // segment, combo (site 8s -> MSB)
  const int c   = l & 15, p = l >> 4;

  const int srcA = (l & 15) | ((l & 16) << 1);
  const int srcB = srcA | 16;
  const bool hi5 = (l & 32) != 0;

  // B := T[site 8s+7] as B-frags from Tt
  frag_u B[2][4];
  {
    int m7 = (8 * s + 7) * 2 + (cmb & 1);
    const unsigned short* base = Tt + ((size_t)m7 << 12);
#pragma unroll
    for (int ks = 0; ks < 2; ++ks)
#pragma unroll
      for (int nj = 0; nj < 4; ++nj)
        B[ks][nj].i = *reinterpret_cast<const int4v*>(base + (c + 16 * nj) * 64 + 32 * ks + 8 * p);
  }

  // sites j = 6..1 : B := T[8s+j][digit] * B
#pragma unroll
  for (int j = 6; j >= 1; --j) {
    int m = (8 * s + j) * 2 + ((cmb >> (7 - j)) & 1);
    const unsigned short* abase = Tn + ((size_t)m << 12);
    frag_u A[4][2];
#pragma unroll
    for (int mi = 0; mi < 4; ++mi)
#pragma unroll
      for (int ks = 0; ks < 2; ++ks)
        A[mi][ks].i = *reinterpret_cast<const int4v*>(abase + (c + 16 * mi) * 64 + 32 * ks + 8 * p);

    int pk[4][4][2];
#pragma unroll
    for (int mi = 0; mi < 4; ++mi)
#pragma unroll
      for (int nj = 0; nj < 4; ++nj) {
        f32x4 d = {0.f, 0.f, 0.f, 0.f};
        d = MFMA16(A[mi][0].v, B[0][nj].v, d);
        d = MFMA16(A[mi][1].v, B[1][nj].v, d);
        asm("v_cvt_pk_bf16_f32 %0, %1, %2" : "=v"(pk[mi][nj][0]) : "v"(d[0]), "v"(d[1]));
        asm("v_cvt_pk_bf16_f32 %0, %1, %2" : "=v"(pk[mi][nj][1]) : "v"(d[2]), "v"(d[3]));
      }
#pragma unroll
    for (int ks = 0; ks < 2; ++ks)
#pragma unroll
      for (int nj = 0; nj < 4; ++nj) {
        int lo0 = pk[2 * ks][nj][0],     lo1 = pk[2 * ks][nj][1];
        int hi0 = pk[2 * ks + 1][nj][0], hi1 = pk[2 * ks + 1][nj][1];
        int a0 = __shfl(lo0, srcA, 64), b0 = __shfl(hi0, srcA, 64);
        int a1 = __shfl(lo1, srcA, 64), b1 = __shfl(hi1, srcA, 64);
        int a2 = __shfl(lo0, srcB, 64), b2 = __shfl(hi0, srcB, 64);
        int a3 = __shfl(lo1, srcB, 64), b3 = __shfl(hi1, srcB, 64);
        int4v nb = { hi5 ? b0 : a0, hi5 ? b1 : a1, hi5 ? b2 : a2, hi5 ? b3 : a3 };
        B[ks][nj].i = nb;
      }
  }

  // final site 8s: full D = A(T) x B; store P8n (s<7) and P8t (s==3 || s==7)
  {
    int m0 = (8 * s) * 2 + ((cmb >> 7) & 1);
    const unsigned short* abase = Tn + ((size_t)m0 << 12);
    frag_u A[4][2];
#pragma unroll
    for (int mi = 0; mi < 4; ++mi)
#pragma unroll
      for (int ks = 0; ks < 2; ++ks)
        A[mi][ks].i = *reinterpret_cast<const int4v*>(abase + (c + 16 * mi) * 64 + 32 * ks + 8 * p);

    unsigned short* ON = P8n + (((size_t)w) << 12);
    unsigned short* OT = P8t + (((size_t)w) << 12);
    const bool wantN = (s < 7);
    const bool wantT = (s == 3) || (s == 7);
#pragma unroll
    for (int mi = 0; mi < 4; ++mi)
#pragma unroll
      for (int nj = 0; nj < 4; ++nj) {
        f32x4 d = {0.f, 0.f, 0.f, 0.f};
        d = MFMA16(A[mi][0].v, B[0][nj].v, d);
        d = MFMA16(A[mi][1].v, B[1][nj].v, d);
        if (wantN) {               // row-major (A-frag source for chain)
          int row0 = 16 * mi + 4 * p, col = 16 * nj + c;
#pragma unroll
          for (int r = 0; r < 4; ++r)
            ON[(size_t)(row0 + r) * 64 + col] = f2bf(d[r]);
        }
        if (wantT) {               // transposed (B-frag source for chain inits)
          int n = 16 * nj + c, m0r = 16 * mi + 4 * p;
          ushort4 pkv;
          pkv.x = f2bf(d[0]); pkv.y = f2bf(d[1]);
          pkv.z = f2bf(d[2]); pkv.w = f2bf(d[3]);
          *reinterpret_cast<ushort4*>(OT + (size_t)n * 64 + m0r) = pkv;
        }
      }
  }
}

// ---------------- phase 2: split chain, two waves per batch ----------------
#define ELROW 72   // LDS row stride (u16): 144 B, verified pad (round 9)

__global__ __launch_bounds__(256) void chain_split_kernel(const int* __restrict__ x,
                                                          const unsigned short* __restrict__ P8n,
                                                          const unsigned short* __restrict__ P8t,
                                                          float* __restrict__ out) {
  __shared__ __align__(16) unsigned short EL[2][64 * ELROW];

  const int tid = threadIdx.x;
  const int l   = tid & 63;
  const int w   = tid >> 6;          // 0..3
  const int bl  = w >> 1;            // local batch 0/1
  const int h   = w & 1;             // half: 0 -> segs 0..3, 1 -> segs 4..7
  const int b   = blockIdx.x * 2 + bl;
  const int c   = l & 15, p = l >> 4;

  // segment indices (combo: leftmost site of segment = MSB)
  unsigned long long mask = __ballot((x[b * 64 + l] & 1) != 0);
  int idx[8];
#pragma unroll
  for (int s = 0; s < 8; ++s) {
    unsigned byte = (unsigned)((mask >> (8 * s)) & 0xFFull);
    idx[s] = (int)(__builtin_bitreverse32(byte) >> 24);
  }

  const int srcA = (l & 15) | ((l & 16) << 1);
  const int srcB = srcA | 16;
  const bool hi5 = (l & 32) != 0;

  // B := P8t[4h+3][idx]  (transposed layout available for s=3 and s=7)
  frag_u B[2][4];
  {
    const int sg = 4 * h + 3;
    const unsigned short* base = P8t + (((size_t)(sg * 256 + idx[sg])) << 12);
#pragma unroll
    for (int ks = 0; ks < 2; ++ks)
#pragma unroll
      for (int nj = 0; nj < 4; ++nj)
        B[ks][nj].i = *reinterpret_cast<const int4v*>(base + (c + 16 * nj) * 64 + 32 * ks + 8 * p);
  }

  // shuffle-multiplies: h0: s = 2,1 ; h1: s = 6,5,4   (s = 4h+2-t)
  for (int t = 0; t < 2 + h; ++t) {
    const int s = 4 * h + 2 - t;
    const unsigned short* abase = P8n + (((size_t)(s * 256 + idx[s])) << 12);
    frag_u A[4][2];
#pragma unroll
    for (int mi = 0; mi < 4; ++mi)
#pragma unroll
      for (int ks = 0; ks < 2; ++ks)
        A[mi][ks].i = *reinterpret_cast<const int4v*>(abase + (c + 16 * mi) * 64 + 32 * ks + 8 * p);

    int pk[4][4][2];
#pragma unroll
    for (int mi = 0; mi < 4; ++mi)
#pragma unroll
      for (int nj = 0; nj < 4; ++nj) {
        f32x4 d = {0.f, 0.f, 0.f, 0.f};
        d = MFMA16(A[mi][0].v, B[0][nj].v, d);
        d = MFMA16(A[mi][1].v, B[1][nj].v, d);
        asm("v_cvt_pk_bf16_f32 %0, %1, %2" : "=v"(pk[mi][nj][0]) : "v"(d[0]), "v"(d[1]));
        asm("v_cvt_pk_bf16_f32 %0, %1, %2" : "=v"(pk[mi][nj][1]) : "v"(d[2]), "v"(d[3]));
      }
#pragma unroll
    for (int ks = 0; ks < 2; ++ks)
#pragma unroll
      for (int nj = 0; nj < 4; ++nj) {
        int lo0 = pk[2 * ks][nj][0],     lo1 = pk[2 * ks][nj][1];
        int hi0 = pk[2 * ks + 1][nj][0], hi1 = pk[2 * ks + 1][nj][1];
        int a0 = __shfl(lo0, srcA, 64), b0 = __shfl(hi0, srcA, 64);
        int a1 = __shfl(lo1, srcA, 64), b1 = __shfl(hi1, srcA, 64);
        int a2 = __shfl(lo0, srcB, 64), b2 = __shfl(hi0, srcB, 64);
        int a3 = __shfl(lo1, srcB, 64), b3 = __shfl(hi1, srcB, 64);
        int4v nb = { hi5 ? b0 : a0, hi5 ? b1 : a1, hi5 ? b2 : a2, hi5 ? b3 : a3 };
        B[ks][nj].i = nb;
      }
  }

  if (h == 0) {
    // final full: M_L = A(P8n[0][idx0]) * B ; store bf16 row-major to EL[bl]
    const unsigned short* abase = P8n + (((size_t)idx[0]) << 12);
    frag_u A[4][2];
#pragma unroll
    for (int mi = 0; mi < 4; ++mi)
#pragma unroll
      for (int ks = 0; ks < 2; ++ks)
        A[mi][ks].i = *reinterpret_cast<const int4v*>(abase + (c + 16 * mi) * 64 + 32 * ks + 8 * p);
#pragma unroll
    for (int mi = 0; mi < 4; ++mi)
#pragma unroll
      for (int nj = 0; nj < 4; ++nj) {
        f32x4 d = {0.f, 0.f, 0.f, 0.f};
        d = MFMA16(A[mi][0].v, B[0][nj].v, d);
        d = MFMA16(A[mi][1].v, B[1][nj].v, d);
        int row0 = 16 * mi + 4 * p, col = 16 * nj + c;
#pragma unroll
        for (int r = 0; r < 4; ++r)
          EL[bl][(row0 + r) * ELROW + col] = f2bf(d[r]);
      }
  }
  __syncthreads();
  if (h == 1) {
    // psi = tr(M_L * M_R): A-frags of M_L from EL, B = M_R in regs; diag tiles only
    float psum = 0.f;
#pragma unroll
    for (int t2 = 0; t2 < 4; ++t2) {
      frag_u A0, A1;
      A0.i = *reinterpret_cast<const int4v*>(&EL[bl][(c + 16 * t2) * ELROW + 8 * p]);
      A1.i = *reinterpret_cast<const int4v*>(&EL[bl][(c + 16 * t2) * ELROW + 32 + 8 * p]);
      f32x4 d = {0.f, 0.f, 0.f, 0.f};
      d = MFMA16(A0.v, B[0][t2].v, d);
      d = MFMA16(A1.v, B[1][t2].v, d);
      if (p == (c >> 2)) {
#pragma unroll
        for (int r = 0; r < 4; ++r) psum += (r == (c & 3)) ? d[r] : 0.f;
      }
    }
#pragma unroll
    for (int o = 32; o > 0; o >>= 1) psum += __shfl_down(psum, o, 64);
    if (l == 0) out[b] = logf(fabsf(psum));
  }
}

// ---------------- launch ----------------
extern "C" void kernel_launch(void* const* d_in, const int* in_sizes, int n_in,
                              void* d_out, int out_size, void* d_ws, size_t ws_size,
                              hipStream_t stream) {
  const int*   x     = (const int*)d_in[0];     // [4096][64] int32
  const float* param = (const float*)d_in[1];   // [64][2][64][64] f32
  float* out = (float*)d_out;                   // 4096 floats: log|psi_b|

  char* ws = (char*)d_ws;   // 256 MiB available; we use 40 MiB
  unsigned short* Tn  = (unsigned short*)(ws + (0ull  << 20));
  unsigned short* Tt  = (unsigned short*)(ws + (1ull  << 20));
  unsigned short* P8n = (unsigned short*)(ws + (8ull  << 20));
  unsigned short* P8t = (unsigned short*)(ws + (24ull << 20));

  prep_kernel<<<2048, 256, 0, stream>>>(param, Tn, Tt);
  build_p8_kernel<<<512, 256, 0, stream>>>(Tn, Tt, P8n, P8t);
  chain_split_kernel<<<2048, 256, 0, stream>>>(x, P8n, P8t, out);
}